// Round 1
// baseline (1301.042 us; speedup 1.0000x reference)
//
#include <hip/hip_runtime.h>

// CrossEntropyLoss: B=8192 rows, V=32000 cols, fp32.
// loss = ( sum_i [ log(sum_j exp(out[i,j]) + 1e-5) - out[i, label[i]] ] ) / B
// Memory-bound: 1.049 GB single pass. One block per row, float4 loads.

#define CE_B 8192
#define CE_V 32000
#define CE_EPS 1e-5f
#define CE_BLOCK 256

__global__ __launch_bounds__(CE_BLOCK) void ce_row_kernel(
    const float* __restrict__ out, const int* __restrict__ label,
    float* __restrict__ acc) {
  const int row = blockIdx.x;
  const float4* rowp = (const float4*)(out + (size_t)row * CE_V);
  const int n4 = CE_V / 4;  // 8000 float4 per row

  float s = 0.f;
  for (int j = threadIdx.x; j < n4; j += CE_BLOCK) {
    float4 v = rowp[j];
    s += __expf(v.x) + __expf(v.y) + __expf(v.z) + __expf(v.w);
  }

  // wave (64-lane) shuffle reduction
  for (int off = 32; off > 0; off >>= 1) s += __shfl_down(s, off, 64);

  __shared__ float wsum[CE_BLOCK / 64];
  const int wid = threadIdx.x >> 6;
  if ((threadIdx.x & 63) == 0) wsum[wid] = s;
  __syncthreads();

  if (threadIdx.x == 0) {
    float tot = 0.f;
#pragma unroll
    for (int w = 0; w < CE_BLOCK / 64; ++w) tot += wsum[w];
    const int lab = label[row];
    float contrib = __logf(tot + CE_EPS) - out[(size_t)row * CE_V + lab];
    atomicAdd(acc, contrib);  // device-scope by default on CDNA
  }
}

__global__ void ce_finalize(const float* __restrict__ acc,
                            float* __restrict__ loss) {
  if (threadIdx.x == 0) loss[0] = acc[0] / (float)CE_B;
}

extern "C" void kernel_launch(void* const* d_in, const int* in_sizes, int n_in,
                              void* d_out, int out_size, void* d_ws,
                              size_t ws_size, hipStream_t stream) {
  const float* output = (const float*)d_in[0];
  const int* label = (const int*)d_in[1];
  float* acc = (float*)d_ws;  // 4-byte accumulator in workspace

  // d_ws is re-poisoned to 0xAA before every launch — zero the accumulator.
  hipMemsetAsync(d_ws, 0, sizeof(float), stream);

  ce_row_kernel<<<CE_B, CE_BLOCK, 0, stream>>>(output, label, acc);
  ce_finalize<<<1, 64, 0, stream>>>(acc, (float*)d_out);
}

// Round 2
// 1283.942 us; speedup vs baseline: 1.0133x; 1.0133x over previous
//
#include <hip/hip_runtime.h>

// CrossEntropyLoss: B=8192 rows, V=32000 cols, fp32.
// loss = ( sum_i [ log(sum_j exp(out[i,j]) + 1e-5) - out[i, label[i]] ] ) / B
// Memory-bound: 1.049 GB single pass (167 us floor @ 6.3 TB/s).
// Round 2: no atomics, no memset — row kernel writes per-row contribs to d_ws,
// finalize kernel tree-reduces 8192 floats. Removes same-address atomic
// serialization tail and the 4B memset graph node.

#define CE_B 8192
#define CE_V 32000
#define CE_EPS 1e-5f
#define CE_BLOCK 256

__global__ __launch_bounds__(CE_BLOCK) void ce_row_kernel(
    const float* __restrict__ out, const int* __restrict__ label,
    float* __restrict__ contrib) {
  const int row = blockIdx.x;
  const float4* rowp = (const float4*)(out + (size_t)row * CE_V);
  const int n4 = CE_V / 4;  // 8000 float4 per row

  float s = 0.f;
  for (int j = threadIdx.x; j < n4; j += CE_BLOCK) {
    float4 v = rowp[j];
    s += __expf(v.x) + __expf(v.y) + __expf(v.z) + __expf(v.w);
  }

  // wave (64-lane) shuffle reduction
  for (int off = 32; off > 0; off >>= 1) s += __shfl_down(s, off, 64);

  __shared__ float wsum[CE_BLOCK / 64];
  const int wid = threadIdx.x >> 6;
  if ((threadIdx.x & 63) == 0) wsum[wid] = s;
  __syncthreads();

  if (threadIdx.x == 0) {
    float tot = 0.f;
#pragma unroll
    for (int w = 0; w < CE_BLOCK / 64; ++w) tot += wsum[w];
    const int lab = label[row];
    contrib[row] = __logf(tot + CE_EPS) - out[(size_t)row * CE_V + lab];
  }
}

// Single-block reduction of CE_B contribs -> loss/B.
__global__ __launch_bounds__(1024) void ce_finalize(
    const float* __restrict__ contrib, float* __restrict__ loss) {
  float s = 0.f;
  for (int i = threadIdx.x; i < CE_B; i += 1024) s += contrib[i];

  for (int off = 32; off > 0; off >>= 1) s += __shfl_down(s, off, 64);

  __shared__ float wsum[1024 / 64];
  const int wid = threadIdx.x >> 6;
  if ((threadIdx.x & 63) == 0) wsum[wid] = s;
  __syncthreads();

  if (threadIdx.x == 0) {
    float tot = 0.f;
#pragma unroll
    for (int w = 0; w < 1024 / 64; ++w) tot += wsum[w];
    loss[0] = tot / (float)CE_B;
  }
}

extern "C" void kernel_launch(void* const* d_in, const int* in_sizes, int n_in,
                              void* d_out, int out_size, void* d_ws,
                              size_t ws_size, hipStream_t stream) {
  const float* output = (const float*)d_in[0];
  const int* label = (const int*)d_in[1];
  float* contrib = (float*)d_ws;  // 8192 floats of scratch

  ce_row_kernel<<<CE_B, CE_BLOCK, 0, stream>>>(output, label, contrib);
  ce_finalize<<<1, 1024, 0, stream>>>(contrib, (float*)d_out);
}